// Round 7
// baseline (322.468 us; speedup 1.0000x reference)
//
#include <hip/hip_runtime.h>
#include <stdint.h>

#define NS 32
#define NIN 2048
#define NOUT 2048

// ================= Threefry-2x32, 4 independent chains, hand-scheduled asm =================
// rot r == v_alignbit_b32(v,v,32-r): shifts 19,17,6,26 / 15,3,16,8 (inline consts).
// NON-volatile pure asm: compiler may schedule loads around it. Validated bit-exact (R4-R6).

#define ADD4                                 \
    "v_add_u32 %[t0], %[t0], %[a0]\n\t"      \
    "v_add_u32 %[t1], %[t1], %[a1]\n\t"      \
    "v_add_u32 %[t2], %[t2], %[a2]\n\t"      \
    "v_add_u32 %[t3], %[t3], %[a3]\n\t"

#define ADDK4                                \
    "v_add_u32 %[t0], %[k0], %[a0]\n\t"      \
    "v_add_u32 %[t1], %[k0], %[a1]\n\t"      \
    "v_add_u32 %[t2], %[k0], %[a2]\n\t"      \
    "v_add_u32 %[t3], %[k0], %[a3]\n\t"

#define ROT4(sh)                                          \
    "v_alignbit_b32 %[a0], %[a0], %[a0], " sh "\n\t"      \
    "v_alignbit_b32 %[a1], %[a1], %[a1], " sh "\n\t"      \
    "v_alignbit_b32 %[a2], %[a2], %[a2], " sh "\n\t"      \
    "v_alignbit_b32 %[a3], %[a3], %[a3], " sh "\n\t"

#define XOR4                                 \
    "v_xor_b32 %[a0], %[a0], %[t0]\n\t"      \
    "v_xor_b32 %[a1], %[a1], %[t1]\n\t"      \
    "v_xor_b32 %[a2], %[a2], %[t2]\n\t"      \
    "v_xor_b32 %[a3], %[a3], %[t3]\n\t"

#define TF4R(sh) ADD4 ROT4(sh) XOR4

#define TF4INJ(ka, kb)                           \
    "v_add_u32 %[t0], %[" ka "], %[t0]\n\t"      \
    "v_add_u32 %[t1], %[" ka "], %[t1]\n\t"      \
    "v_add_u32 %[t2], %[" ka "], %[t2]\n\t"      \
    "v_add_u32 %[t3], %[" ka "], %[t3]\n\t"      \
    "v_add_u32 %[a0], %[" kb "], %[a0]\n\t"      \
    "v_add_u32 %[a1], %[" kb "], %[a1]\n\t"      \
    "v_add_u32 %[a2], %[" kb "], %[a2]\n\t"      \
    "v_add_u32 %[a3], %[" kb "], %[a3]\n\t"

// a_i in: counter+k1.  a_i out: x0^x1 (folded random bits).
__device__ __forceinline__ void tf_fold4(uint32_t k0, uint32_t k1, uint32_t k2,
                                         uint32_t& a0, uint32_t& a1,
                                         uint32_t& a2, uint32_t& a3) {
    uint32_t t0, t1, t2, t3;
    const uint32_t c1 = k2 + 1u, c2 = k0 + 2u, c3 = k1 + 3u, c4 = k2 + 4u, c5 = k0 + 5u;
    asm(ADDK4 ROT4("19") XOR4                       // rounds 1-4 (rot 13,15,26,6)
        TF4R("17") TF4R("6") TF4R("26")
        TF4INJ("k1", "c1")
        TF4R("15") TF4R("3") TF4R("16") TF4R("8")   // rounds 5-8 (rot 17,29,16,24)
        TF4INJ("k2", "c2")
        TF4R("19") TF4R("17") TF4R("6") TF4R("26")  // rounds 9-12
        TF4INJ("k0", "c3")
        TF4R("15") TF4R("3") TF4R("16") TF4R("8")   // rounds 13-16
        TF4INJ("k1", "c4")
        TF4R("19") TF4R("17") TF4R("6") TF4R("26")  // rounds 17-20
        TF4INJ("k2", "c5")
        XOR4                                        // fold x0^x1
        : [a0] "+v"(a0), [a1] "+v"(a1), [a2] "+v"(a2), [a3] "+v"(a3),
          [t0] "=&v"(t0), [t1] "=&v"(t1), [t2] "=&v"(t2), [t3] "=&v"(t3)
        : [k0] "s"(k0), [k1] "s"(k1), [k2] "s"(k2),
          [c1] "s"(c1), [c2] "s"(c2), [c3] "s"(c3), [c4] "s"(c4), [c5] "s"(c5));
}

// ---------- bits -> u in (-1,1) and l2 = log2(1-u^2) ----------
__device__ __forceinline__ void ul2_from_bits(uint32_t bits, float& u, float& l2) {
    const float LO = __uint_as_float(0xBF7FFFFFu);  // nextafter(-1.f, 0.f)
    float f = __uint_as_float((bits >> 9) | 0x3f800000u) - 1.0f;  // [0,1)
    u = fmaf(f, 2.0f, LO);
    l2 = __log2f(fmaf(-u, u, 1.0f));  // raw v_log_f32; ln2 folded into poly arg
}

// sqrt(2)*erfinv poly, sqrt2 folded into coefficients, arg from log2 (validated R5/R6).
// fast branch iff l2 > -7.2134752  (w = -ln2*l2 < 5)
__device__ __forceinline__ float erfinv2_fast(float l2) {
    float t = fmaf(l2, -0.69314718f, -2.5f);  // w - 2.5
    float p = 3.9739403e-08f;
    p = fmaf(p, t, 4.8546628e-07f);
    p = fmaf(p, t, -4.9828418e-06f);
    p = fmaf(p, t, -6.2105079e-06f);
    p = fmaf(p, t, 3.0912069e-04f);
    p = fmaf(p, t, -1.7730336e-03f);
    p = fmaf(p, t, -5.9081371e-03f);
    p = fmaf(p, t, 0.34878364f);
    p = fmaf(p, t, 2.1233153f);
    return p;
}

__device__ __forceinline__ float erfinv2_slow(float l2) {
    float w = l2 * -0.69314718f;
    float t = __fsqrt_rn(w) - 3.0f;
    float p = -2.8314685e-04f;
    p = fmaf(p, t, 1.4276577e-04f);
    p = fmaf(p, t, 1.9082652e-03f);
    p = fmaf(p, t, -5.1950077e-03f);
    p = fmaf(p, t, 8.1169428e-03f);
    p = fmaf(p, t, -1.0779843e-02f);
    p = fmaf(p, t, 1.3348618e-02f);
    p = fmaf(p, t, 1.4165813f);
    p = fmaf(p, t, 4.0064342f);
    return p;
}

// scalar threefry fold (bias path)
__device__ __forceinline__ uint32_t rotl32c(uint32_t v, uint32_t r) {
    return __builtin_amdgcn_alignbit(v, v, 32u - r);
}
#define TF_R1(x0, x1, r) do { x0 += x1; x1 = rotl32c(x1, r) ^ x0; } while (0)
__device__ __forceinline__ uint32_t tf_fold1(uint32_t k0, uint32_t k1, uint32_t k2,
                                             uint32_t x1in) {
    uint32_t x0 = k0 + x1in;
    uint32_t x1 = rotl32c(x1in, 13) ^ x0;
    TF_R1(x0, x1, 15); TF_R1(x0, x1, 26); TF_R1(x0, x1, 6);
    x0 += k1; x1 += k2 + 1u;
    TF_R1(x0, x1, 17); TF_R1(x0, x1, 29); TF_R1(x0, x1, 16); TF_R1(x0, x1, 24);
    x0 += k2; x1 += k0 + 2u;
    TF_R1(x0, x1, 13); TF_R1(x0, x1, 15); TF_R1(x0, x1, 26); TF_R1(x0, x1, 6);
    x0 += k0; x1 += k1 + 3u;
    TF_R1(x0, x1, 17); TF_R1(x0, x1, 29); TF_R1(x0, x1, 16); TF_R1(x0, x1, 24);
    x0 += k1; x1 += k2 + 4u;
    TF_R1(x0, x1, 13); TF_R1(x0, x1, 15); TF_R1(x0, x1, 26); TF_R1(x0, x1, 6);
    x0 += k2; x1 += k0 + 5u;
    return x0 ^ x1;
}

__device__ __forceinline__ float normal_from_bits(uint32_t bits) {
    float u, l2;
    ul2_from_bits(bits, u, l2);
    float p = (l2 > -7.2134752f) ? erfinv2_fast(l2) : erfinv2_slow(l2);
    return p * u;
}

// 4 eps tail: bits b0..b3 -> e0..e3
#define TAIL4(B0, B1, B2, B3, E0, E1, E2, E3)                                   \
    {                                                                           \
        float u0, u1, u2, u3, l0, l1, l2v, l3;                                  \
        ul2_from_bits(B0, u0, l0);                                              \
        ul2_from_bits(B1, u1, l1);                                              \
        ul2_from_bits(B2, u2, l2v);                                             \
        ul2_from_bits(B3, u3, l3);                                              \
        float q0 = erfinv2_fast(l0);                                            \
        float q1 = erfinv2_fast(l1);                                            \
        float q2 = erfinv2_fast(l2v);                                           \
        float q3 = erfinv2_fast(l3);                                            \
        if (__any(fminf(fminf(l0, l1), fminf(l2v, l3)) <= -7.2134752f)) {       \
            if (l0 <= -7.2134752f) q0 = erfinv2_slow(l0);                       \
            if (l1 <= -7.2134752f) q1 = erfinv2_slow(l1);                       \
            if (l2v <= -7.2134752f) q2 = erfinv2_slow(l2v);                     \
            if (l3 <= -7.2134752f) q3 = erfinv2_slow(l3);                       \
        }                                                                       \
        E0 = q0 * u0;                                                           \
        E1 = q1 * u1;                                                           \
        E2 = q2 * u2;                                                           \
        E3 = q3 * u3;                                                           \
    }

// Block = o (row read once, coalesced). Wave w owns s in [8w, 8w+8). Lane spans i.
// Register-prefetch pipeline: iteration j issues j+1's 10 loads up front, consumes
// the previous generation -> the s_waitcnt lands ~700 instrs after issue.
// __launch_bounds__(256,4): VGPR cap 128 (4 waves/SIMD, same occupancy as R6's 53%).
__global__ __launch_bounds__(256, 4) void bayes_linear_kernel(
    const float* __restrict__ x, const float* __restrict__ wmu,
    const float* __restrict__ wsg, const float* __restrict__ bmu,
    const float* __restrict__ bsg, float* __restrict__ out,
    uint32_t kw0, uint32_t kw1, uint32_t kb0, uint32_t kb1) {
    const uint32_t o = blockIdx.x;
    const uint32_t tid = threadIdx.x;
    const uint32_t lane = tid & 63u;
    const uint32_t wv = (uint32_t)__builtin_amdgcn_readfirstlane((int)(tid >> 6));
    const uint32_t sb = wv * 8u;  // wave-uniform first s

    const uint32_t kw2 = kw0 ^ kw1 ^ 0x1BD11BDAu;
    const uint32_t kb2 = kb0 ^ kb1 ^ 0x1BD11BDAu;

    const float* __restrict__ mrow = wmu + o * NIN;
    const float* __restrict__ grow = wsg + o * NIN;
    const float* __restrict__ xr0 = x + (sb + 0u) * NIN;
    const float* __restrict__ xr1 = x + (sb + 1u) * NIN;
    const float* __restrict__ xr2 = x + (sb + 2u) * NIN;
    const float* __restrict__ xr3 = x + (sb + 3u) * NIN;
    const float* __restrict__ xr4 = x + (sb + 4u) * NIN;
    const float* __restrict__ xr5 = x + (sb + 5u) * NIN;
    const float* __restrict__ xr6 = x + (sb + 6u) * NIN;
    const float* __restrict__ xr7 = x + (sb + 7u) * NIN;

    // weight counter: p = s*2^22 + o*2^11 + i (+k1 pre-added)
    const uint32_t pw = (sb << 22) + (o << 11) + kw1;

    float a0 = 0.f, a1 = 0.f, a2 = 0.f, a3 = 0.f;
    float a4 = 0.f, a5 = 0.f, a6 = 0.f, a7 = 0.f;

    // --- prologue: load generation 0 ---
    float mu_c = mrow[lane];
    float sg_c = grow[lane];
    float xc0 = xr0[lane], xc1 = xr1[lane], xc2 = xr2[lane], xc3 = xr3[lane];
    float xc4 = xr4[lane], xc5 = xr5[lane], xc6 = xr6[lane], xc7 = xr7[lane];

#pragma unroll 1
    for (uint32_t j = 0; j < NIN; j += 64u) {
        // --- prefetch generation j+1 (wave-uniform wrap on last iter; harmless) ---
        const uint32_t jn = (j + 64u < (uint32_t)NIN) ? (j + 64u) : 0u;
        const uint32_t in_ = jn + lane;
        const float mu_n = mrow[in_];
        const float sg_n = grow[in_];
        const float xn0 = xr0[in_], xn1 = xr1[in_], xn2 = xr2[in_], xn3 = xr3[in_];
        const float xn4 = xr4[in_], xn5 = xr5[in_], xn6 = xr6[in_], xn7 = xr7[in_];

        // --- compute with current generation ---
        const uint32_t pb = pw + j + lane;

        uint32_t b0 = pb, b1 = pb + (1u << 22), b2 = pb + (2u << 22), b3 = pb + (3u << 22);
        tf_fold4(kw0, kw1, kw2, b0, b1, b2, b3);
        float e0, e1, e2, e3;
        TAIL4(b0, b1, b2, b3, e0, e1, e2, e3);
        a0 = fmaf(fmaf(sg_c, e0, mu_c), xc0, a0);
        a1 = fmaf(fmaf(sg_c, e1, mu_c), xc1, a1);
        a2 = fmaf(fmaf(sg_c, e2, mu_c), xc2, a2);
        a3 = fmaf(fmaf(sg_c, e3, mu_c), xc3, a3);

        uint32_t c0 = pb + (4u << 22), c1 = pb + (5u << 22), c2 = pb + (6u << 22), c3 = pb + (7u << 22);
        tf_fold4(kw0, kw1, kw2, c0, c1, c2, c3);
        float e4, e5, e6, e7;
        TAIL4(c0, c1, c2, c3, e4, e5, e6, e7);
        a4 = fmaf(fmaf(sg_c, e4, mu_c), xc4, a4);
        a5 = fmaf(fmaf(sg_c, e5, mu_c), xc5, a5);
        a6 = fmaf(fmaf(sg_c, e6, mu_c), xc6, a6);
        a7 = fmaf(fmaf(sg_c, e7, mu_c), xc7, a7);

        // --- rotate generations ---
        mu_c = mu_n; sg_c = sg_n;
        xc0 = xn0; xc1 = xn1; xc2 = xn2; xc3 = xn3;
        xc4 = xn4; xc5 = xn5; xc6 = xn6; xc7 = xn7;
    }

    // butterfly all-reduce each accumulator across the wave
#define RED(v)                          \
    v += __shfl_xor(v, 32, 64);         \
    v += __shfl_xor(v, 16, 64);         \
    v += __shfl_xor(v, 8, 64);          \
    v += __shfl_xor(v, 4, 64);          \
    v += __shfl_xor(v, 2, 64);          \
    v += __shfl_xor(v, 1, 64);
    RED(a0) RED(a1) RED(a2) RED(a3) RED(a4) RED(a5) RED(a6) RED(a7)
#undef RED

    if (lane < 8u) {
        float mysum = a0;
        mysum = (lane == 1u) ? a1 : mysum;
        mysum = (lane == 2u) ? a2 : mysum;
        mysum = (lane == 3u) ? a3 : mysum;
        mysum = (lane == 4u) ? a4 : mysum;
        mysum = (lane == 5u) ? a5 : mysum;
        mysum = (lane == 6u) ? a6 : mysum;
        mysum = (lane == 7u) ? a7 : mysum;
        const uint32_t s = sb + lane;
        const uint32_t pbb = s * (uint32_t)NOUT + o + kb1;  // eps_b index: s*OUT + o
        const float eb = normal_from_bits(tf_fold1(kb0, kb1, kb2, pbb));
        out[s * NOUT + o] = mysum + fmaf(bsg[o], eb, bmu[o]);
    }
}

// ---------- host-side threefry for key derivation ----------
#define TF_ROUND_H(x0, x1, r)                     \
    do {                                          \
        x0 += x1;                                 \
        x1 = (x1 << (r)) | (x1 >> (32 - (r)));    \
        x1 ^= x0;                                 \
    } while (0)

static void tf2x32_host(uint32_t k0, uint32_t k1, uint32_t x0, uint32_t x1,
                        uint32_t* y0, uint32_t* y1) {
    uint32_t k2 = k0 ^ k1 ^ 0x1BD11BDAu;
    x0 += k0; x1 += k1;
    TF_ROUND_H(x0, x1, 13); TF_ROUND_H(x0, x1, 15); TF_ROUND_H(x0, x1, 26); TF_ROUND_H(x0, x1, 6);
    x0 += k1; x1 += k2 + 1u;
    TF_ROUND_H(x0, x1, 17); TF_ROUND_H(x0, x1, 29); TF_ROUND_H(x0, x1, 16); TF_ROUND_H(x0, x1, 24);
    x0 += k2; x1 += k0 + 2u;
    TF_ROUND_H(x0, x1, 13); TF_ROUND_H(x0, x1, 15); TF_ROUND_H(x0, x1, 26); TF_ROUND_H(x0, x1, 6);
    x0 += k0; x1 += k1 + 3u;
    TF_ROUND_H(x0, x1, 17); TF_ROUND_H(x0, x1, 29); TF_ROUND_H(x0, x1, 16); TF_ROUND_H(x0, x1, 24);
    x0 += k1; x1 += k2 + 4u;
    TF_ROUND_H(x0, x1, 13); TF_ROUND_H(x0, x1, 15); TF_ROUND_H(x0, x1, 26); TF_ROUND_H(x0, x1, 6);
    x0 += k2; x1 += k0 + 5u;
    *y0 = x0; *y1 = x1;
}

extern "C" void kernel_launch(void* const* d_in, const int* in_sizes, int n_in,
                              void* d_out, int out_size, void* d_ws, size_t ws_size,
                              hipStream_t stream) {
    const float* x   = (const float*)d_in[0];
    const float* wmu = (const float*)d_in[1];
    const float* wsg = (const float*)d_in[2];
    const float* bmu = (const float*)d_in[3];
    const float* bsg = (const float*)d_in[4];
    float* out = (float*)d_out;

    uint32_t kw0, kw1, kb0, kb1;
    tf2x32_host(0u, 42u, 0u, 0u, &kw0, &kw1);  // wkey = split(key(42))[0]
    tf2x32_host(0u, 42u, 0u, 1u, &kb0, &kb1);  // bkey = split(key(42))[1]

    bayes_linear_kernel<<<NOUT, 256, 0, stream>>>(x, wmu, wsg, bmu, bsg, out,
                                                  kw0, kw1, kb0, kb1);
}

// Round 9
// 314.994 us; speedup vs baseline: 1.0237x; 1.0237x over previous
//
#include <hip/hip_runtime.h>
#include <stdint.h>

#define NS 32
#define NIN 2048
#define NOUT 2048

// ================= Threefry-2x32, 4 independent chains, hand-scheduled asm =================
// rot r == v_alignbit_b32(v,v,32-r): shifts 19,17,6,26 / 15,3,16,8 (inline consts).
// NON-volatile pure asm. Validated bit-exact R4-R7.

#define ADD4                                 \
    "v_add_u32 %[t0], %[t0], %[a0]\n\t"      \
    "v_add_u32 %[t1], %[t1], %[a1]\n\t"      \
    "v_add_u32 %[t2], %[t2], %[a2]\n\t"      \
    "v_add_u32 %[t3], %[t3], %[a3]\n\t"

#define ADDK4                                \
    "v_add_u32 %[t0], %[k0], %[a0]\n\t"      \
    "v_add_u32 %[t1], %[k0], %[a1]\n\t"      \
    "v_add_u32 %[t2], %[k0], %[a2]\n\t"      \
    "v_add_u32 %[t3], %[k0], %[a3]\n\t"

#define ROT4(sh)                                          \
    "v_alignbit_b32 %[a0], %[a0], %[a0], " sh "\n\t"      \
    "v_alignbit_b32 %[a1], %[a1], %[a1], " sh "\n\t"      \
    "v_alignbit_b32 %[a2], %[a2], %[a2], " sh "\n\t"      \
    "v_alignbit_b32 %[a3], %[a3], %[a3], " sh "\n\t"

#define XOR4                                 \
    "v_xor_b32 %[a0], %[a0], %[t0]\n\t"      \
    "v_xor_b32 %[a1], %[a1], %[t1]\n\t"      \
    "v_xor_b32 %[a2], %[a2], %[t2]\n\t"      \
    "v_xor_b32 %[a3], %[a3], %[t3]\n\t"

#define TF4R(sh) ADD4 ROT4(sh) XOR4

#define TF4INJ(ka, kb)                           \
    "v_add_u32 %[t0], %[" ka "], %[t0]\n\t"      \
    "v_add_u32 %[t1], %[" ka "], %[t1]\n\t"      \
    "v_add_u32 %[t2], %[" ka "], %[t2]\n\t"      \
    "v_add_u32 %[t3], %[" ka "], %[t3]\n\t"      \
    "v_add_u32 %[a0], %[" kb "], %[a0]\n\t"      \
    "v_add_u32 %[a1], %[" kb "], %[a1]\n\t"      \
    "v_add_u32 %[a2], %[" kb "], %[a2]\n\t"      \
    "v_add_u32 %[a3], %[" kb "], %[a3]\n\t"

__device__ __forceinline__ void tf_fold4(uint32_t k0, uint32_t k1, uint32_t k2,
                                         uint32_t& a0, uint32_t& a1,
                                         uint32_t& a2, uint32_t& a3) {
    uint32_t t0, t1, t2, t3;
    const uint32_t c1 = k2 + 1u, c2 = k0 + 2u, c3 = k1 + 3u, c4 = k2 + 4u, c5 = k0 + 5u;
    asm(ADDK4 ROT4("19") XOR4                       // rounds 1-4 (rot 13,15,26,6)
        TF4R("17") TF4R("6") TF4R("26")
        TF4INJ("k1", "c1")
        TF4R("15") TF4R("3") TF4R("16") TF4R("8")   // rounds 5-8 (rot 17,29,16,24)
        TF4INJ("k2", "c2")
        TF4R("19") TF4R("17") TF4R("6") TF4R("26")  // rounds 9-12
        TF4INJ("k0", "c3")
        TF4R("15") TF4R("3") TF4R("16") TF4R("8")   // rounds 13-16
        TF4INJ("k1", "c4")
        TF4R("19") TF4R("17") TF4R("6") TF4R("26")  // rounds 17-20
        TF4INJ("k2", "c5")
        XOR4                                        // fold x0^x1
        : [a0] "+v"(a0), [a1] "+v"(a1), [a2] "+v"(a2), [a3] "+v"(a3),
          [t0] "=&v"(t0), [t1] "=&v"(t1), [t2] "=&v"(t2), [t3] "=&v"(t3)
        : [k0] "s"(k0), [k1] "s"(k1), [k2] "s"(k2),
          [c1] "s"(c1), [c2] "s"(c2), [c3] "s"(c3), [c4] "s"(c4), [c5] "s"(c5));
}

// ---------- bits -> u in (-1,1) and l2 = log2(1-u^2) ----------
// JAX-exact two-step map: f = g-1 (exact, Sterbenz), u = fma(f,2,LO).
// u_max = 1 - 3*2^-24 < 1 strictly -> 1-u^2 > 0, log2 finite. (R8's one-op
// fold hit u == 1.0 exactly at the top mantissa -> inf; do NOT re-fold.)
__device__ __forceinline__ void ul2_from_bits(uint32_t bits, float& u, float& l2) {
    const float LO = __uint_as_float(0xBF7FFFFFu);  // nextafter(-1.f, 0.f)
    float f = __uint_as_float((bits >> 9) | 0x3f800000u) - 1.0f;  // [0, 1)
    u = fmaf(f, 2.0f, LO);
    l2 = __log2f(fmaf(-u, u, 1.0f));
}

// sqrt(2)*erfinv, 5-term truncated Giles polys (trunc err <= ~3e-3 per eps;
// ~sqrt(2048)-averaged contribution to out ~0.01-0.03 vs 0.3875 budget).
// fast branch iff l2 > -7.2134752  (w = -ln2*l2 < 5)
__device__ __forceinline__ float erfinv2_fast(float l2) {
    float t = fmaf(l2, -0.69314718f, -2.5f);  // w - 2.5
    float p = 3.0912069e-04f;
    p = fmaf(p, t, -1.7730336e-03f);
    p = fmaf(p, t, -5.9081371e-03f);
    p = fmaf(p, t, 0.34878364f);
    p = fmaf(p, t, 2.1233153f);
    return p;
}

__device__ __forceinline__ float erfinv2_slow(float l2) {
    float w = l2 * -0.69314718f;
    float t = __fsqrt_rn(w) - 3.0f;
    float p = 8.1169428e-03f;
    p = fmaf(p, t, -1.0779843e-02f);
    p = fmaf(p, t, 1.3348618e-02f);
    p = fmaf(p, t, 1.4165813f);
    p = fmaf(p, t, 4.0064342f);
    return p;
}

// scalar threefry fold (bias path)
__device__ __forceinline__ uint32_t rotl32c(uint32_t v, uint32_t r) {
    return __builtin_amdgcn_alignbit(v, v, 32u - r);
}
#define TF_R1(x0, x1, r) do { x0 += x1; x1 = rotl32c(x1, r) ^ x0; } while (0)
__device__ __forceinline__ uint32_t tf_fold1(uint32_t k0, uint32_t k1, uint32_t k2,
                                             uint32_t x1in) {
    uint32_t x0 = k0 + x1in;
    uint32_t x1 = rotl32c(x1in, 13) ^ x0;
    TF_R1(x0, x1, 15); TF_R1(x0, x1, 26); TF_R1(x0, x1, 6);
    x0 += k1; x1 += k2 + 1u;
    TF_R1(x0, x1, 17); TF_R1(x0, x1, 29); TF_R1(x0, x1, 16); TF_R1(x0, x1, 24);
    x0 += k2; x1 += k0 + 2u;
    TF_R1(x0, x1, 13); TF_R1(x0, x1, 15); TF_R1(x0, x1, 26); TF_R1(x0, x1, 6);
    x0 += k0; x1 += k1 + 3u;
    TF_R1(x0, x1, 17); TF_R1(x0, x1, 29); TF_R1(x0, x1, 16); TF_R1(x0, x1, 24);
    x0 += k1; x1 += k2 + 4u;
    TF_R1(x0, x1, 13); TF_R1(x0, x1, 15); TF_R1(x0, x1, 26); TF_R1(x0, x1, 6);
    x0 += k2; x1 += k0 + 5u;
    return x0 ^ x1;
}

__device__ __forceinline__ float normal_from_bits(uint32_t bits) {
    float u, l2;
    ul2_from_bits(bits, u, l2);
    float p = (l2 > -7.2134752f) ? erfinv2_fast(l2) : erfinv2_slow(l2);
    return p * u;
}

// 4 eps tail: bits b0..b3 -> e0..e3
#define TAIL4(B0, B1, B2, B3, E0, E1, E2, E3)                                   \
    {                                                                           \
        float u0, u1, u2, u3, l0, l1, l2v, l3;                                  \
        ul2_from_bits(B0, u0, l0);                                              \
        ul2_from_bits(B1, u1, l1);                                              \
        ul2_from_bits(B2, u2, l2v);                                             \
        ul2_from_bits(B3, u3, l3);                                              \
        float q0 = erfinv2_fast(l0);                                            \
        float q1 = erfinv2_fast(l1);                                            \
        float q2 = erfinv2_fast(l2v);                                           \
        float q3 = erfinv2_fast(l3);                                            \
        if (__any(fminf(fminf(l0, l1), fminf(l2v, l3)) <= -7.2134752f)) {       \
            if (l0 <= -7.2134752f) q0 = erfinv2_slow(l0);                       \
            if (l1 <= -7.2134752f) q1 = erfinv2_slow(l1);                       \
            if (l2v <= -7.2134752f) q2 = erfinv2_slow(l2v);                     \
            if (l3 <= -7.2134752f) q3 = erfinv2_slow(l3);                       \
        }                                                                       \
        E0 = q0 * u0;                                                           \
        E1 = q1 * u1;                                                           \
        E2 = q2 * u2;                                                           \
        E3 = q3 * u3;                                                           \
    }

// 1-wave (64-thread) blocks, grid = NOUT*4: block b -> o = b>>2, s-octet = b&3.
// Lane spans i; per j-iter: 2x tf_fold4 (8 eps), 8 FMAs. No LDS, no barriers.
// __launch_bounds__(64,8): 8 waves/SIMD -> VGPR cap 64 (need ~40).
__global__ __launch_bounds__(64, 8) void bayes_linear_kernel(
    const float* __restrict__ x, const float* __restrict__ wmu,
    const float* __restrict__ wsg, const float* __restrict__ bmu,
    const float* __restrict__ bsg, float* __restrict__ out,
    uint32_t kw0, uint32_t kw1, uint32_t kb0, uint32_t kb1) {
    const uint32_t bid = blockIdx.x;
    const uint32_t o = bid >> 2;
    const uint32_t sb = (bid & 3u) * 8u;  // first s of this wave's octet
    const uint32_t lane = threadIdx.x;

    const uint32_t kw2 = kw0 ^ kw1 ^ 0x1BD11BDAu;
    const uint32_t kb2 = kb0 ^ kb1 ^ 0x1BD11BDAu;

    const float* __restrict__ mrow = wmu + o * NIN;
    const float* __restrict__ grow = wsg + o * NIN;
    const float* __restrict__ xr0 = x + (sb + 0u) * NIN;
    const float* __restrict__ xr1 = x + (sb + 1u) * NIN;
    const float* __restrict__ xr2 = x + (sb + 2u) * NIN;
    const float* __restrict__ xr3 = x + (sb + 3u) * NIN;
    const float* __restrict__ xr4 = x + (sb + 4u) * NIN;
    const float* __restrict__ xr5 = x + (sb + 5u) * NIN;
    const float* __restrict__ xr6 = x + (sb + 6u) * NIN;
    const float* __restrict__ xr7 = x + (sb + 7u) * NIN;

    // weight counter: p = s*2^22 + o*2^11 + i (+k1 pre-added)
    const uint32_t pw = (sb << 22) + (o << 11) + kw1;

    float a0 = 0.f, a1 = 0.f, a2 = 0.f, a3 = 0.f;
    float a4 = 0.f, a5 = 0.f, a6 = 0.f, a7 = 0.f;

#pragma unroll 1
    for (uint32_t j = 0; j < NIN; j += 64u) {
        const uint32_t i = j + lane;
        const float mu = mrow[i];
        const float sg = grow[i];
        const float x0v = xr0[i];
        const float x1v = xr1[i];
        const float x2v = xr2[i];
        const float x3v = xr3[i];
        const float x4v = xr4[i];
        const float x5v = xr5[i];
        const float x6v = xr6[i];
        const float x7v = xr7[i];
        const uint32_t pb = pw + i;

        uint32_t b0 = pb, b1 = pb + (1u << 22), b2 = pb + (2u << 22), b3 = pb + (3u << 22);
        tf_fold4(kw0, kw1, kw2, b0, b1, b2, b3);
        float e0, e1, e2, e3;
        TAIL4(b0, b1, b2, b3, e0, e1, e2, e3);
        a0 = fmaf(fmaf(sg, e0, mu), x0v, a0);
        a1 = fmaf(fmaf(sg, e1, mu), x1v, a1);
        a2 = fmaf(fmaf(sg, e2, mu), x2v, a2);
        a3 = fmaf(fmaf(sg, e3, mu), x3v, a3);

        uint32_t c0 = pb + (4u << 22), c1 = pb + (5u << 22), c2 = pb + (6u << 22), c3 = pb + (7u << 22);
        tf_fold4(kw0, kw1, kw2, c0, c1, c2, c3);
        float e4, e5, e6, e7;
        TAIL4(c0, c1, c2, c3, e4, e5, e6, e7);
        a4 = fmaf(fmaf(sg, e4, mu), x4v, a4);
        a5 = fmaf(fmaf(sg, e5, mu), x5v, a5);
        a6 = fmaf(fmaf(sg, e6, mu), x6v, a6);
        a7 = fmaf(fmaf(sg, e7, mu), x7v, a7);
    }

    // butterfly all-reduce each accumulator across the wave
#define RED(v)                          \
    v += __shfl_xor(v, 32, 64);         \
    v += __shfl_xor(v, 16, 64);         \
    v += __shfl_xor(v, 8, 64);          \
    v += __shfl_xor(v, 4, 64);          \
    v += __shfl_xor(v, 2, 64);          \
    v += __shfl_xor(v, 1, 64);
    RED(a0) RED(a1) RED(a2) RED(a3) RED(a4) RED(a5) RED(a6) RED(a7)
#undef RED

    if (lane < 8u) {
        float mysum = a0;
        mysum = (lane == 1u) ? a1 : mysum;
        mysum = (lane == 2u) ? a2 : mysum;
        mysum = (lane == 3u) ? a3 : mysum;
        mysum = (lane == 4u) ? a4 : mysum;
        mysum = (lane == 5u) ? a5 : mysum;
        mysum = (lane == 6u) ? a6 : mysum;
        mysum = (lane == 7u) ? a7 : mysum;
        const uint32_t s = sb + lane;
        const uint32_t pbb = s * (uint32_t)NOUT + o + kb1;  // eps_b index: s*OUT + o
        const float eb = normal_from_bits(tf_fold1(kb0, kb1, kb2, pbb));
        out[s * NOUT + o] = mysum + fmaf(bsg[o], eb, bmu[o]);
    }
}

// ---------- host-side threefry for key derivation ----------
#define TF_ROUND_H(x0, x1, r)                     \
    do {                                          \
        x0 += x1;                                 \
        x1 = (x1 << (r)) | (x1 >> (32 - (r)));    \
        x1 ^= x0;                                 \
    } while (0)

static void tf2x32_host(uint32_t k0, uint32_t k1, uint32_t x0, uint32_t x1,
                        uint32_t* y0, uint32_t* y1) {
    uint32_t k2 = k0 ^ k1 ^ 0x1BD11BDAu;
    x0 += k0; x1 += k1;
    TF_ROUND_H(x0, x1, 13); TF_ROUND_H(x0, x1, 15); TF_ROUND_H(x0, x1, 26); TF_ROUND_H(x0, x1, 6);
    x0 += k1; x1 += k2 + 1u;
    TF_ROUND_H(x0, x1, 17); TF_ROUND_H(x0, x1, 29); TF_ROUND_H(x0, x1, 16); TF_ROUND_H(x0, x1, 24);
    x0 += k2; x1 += k0 + 2u;
    TF_ROUND_H(x0, x1, 13); TF_ROUND_H(x0, x1, 15); TF_ROUND_H(x0, x1, 26); TF_ROUND_H(x0, x1, 6);
    x0 += k0; x1 += k1 + 3u;
    TF_ROUND_H(x0, x1, 17); TF_ROUND_H(x0, x1, 29); TF_ROUND_H(x0, x1, 16); TF_ROUND_H(x0, x1, 24);
    x0 += k1; x1 += k2 + 4u;
    TF_ROUND_H(x0, x1, 13); TF_ROUND_H(x0, x1, 15); TF_ROUND_H(x0, x1, 26); TF_ROUND_H(x0, x1, 6);
    x0 += k2; x1 += k0 + 5u;
    *y0 = x0; *y1 = x1;
}

extern "C" void kernel_launch(void* const* d_in, const int* in_sizes, int n_in,
                              void* d_out, int out_size, void* d_ws, size_t ws_size,
                              hipStream_t stream) {
    const float* x   = (const float*)d_in[0];
    const float* wmu = (const float*)d_in[1];
    const float* wsg = (const float*)d_in[2];
    const float* bmu = (const float*)d_in[3];
    const float* bsg = (const float*)d_in[4];
    float* out = (float*)d_out;

    uint32_t kw0, kw1, kb0, kb1;
    tf2x32_host(0u, 42u, 0u, 0u, &kw0, &kw1);  // wkey = split(key(42))[0]
    tf2x32_host(0u, 42u, 0u, 1u, &kb0, &kb1);  // bkey = split(key(42))[1]

    bayes_linear_kernel<<<NOUT * 4, 64, 0, stream>>>(x, wmu, wsg, bmu, bsg, out,
                                                     kw0, kw1, kb0, kb1);
}